// Round 1
// baseline (797.683 us; speedup 1.0000x reference)
//
#include <hip/hip_runtime.h>

#define B_ 16
#define H_ 768
#define N_ 2048
#define SCALE 0.03608439182435161f  // 1/sqrt(768)

typedef unsigned short u16;
typedef unsigned int u32;
typedef __attribute__((ext_vector_type(8))) short short8;   // 8 bf16
typedef __attribute__((ext_vector_type(4))) float float4v;  // MFMA acc

__device__ __forceinline__ u16 f2bf(float f) {
  u32 u = __float_as_uint(f);
  u32 r = (u + 0x7FFFu + ((u >> 16) & 1u)) >> 16;  // RNE
  return (u16)r;
}
__device__ __forceinline__ float bf2f(u16 h) { return __uint_as_float(((u32)h) << 16); }
__device__ __forceinline__ u32 pk2(float a, float b) {
  return (u32)f2bf(a) | ((u32)f2bf(b) << 16);
}

// async global->LDS, 16B per lane. LDS dest must be wave-uniform base + lane*16.
__device__ __forceinline__ void dma16(const void* g, void* l) {
  __builtin_amdgcn_global_load_lds(
      (const __attribute__((address_space(1))) void*)g,
      (__attribute__((address_space(3))) void*)l, 16, 0, 0);
}

// ---------------------------------------------------------------------------
// K0: transpose+convert.  which=0: q -> qT bf16 [B][N][H]
//                         which=1: (k+pe) -> keffT bf16 [B][N][H]
__global__ __launch_bounds__(256) void kt_transpose(
    const float* __restrict__ q, const float* __restrict__ k,
    const float* __restrict__ pe, u16* __restrict__ qT, u16* __restrict__ keffT) {
  __shared__ float tile[64][65];  // +1 pad kills bank conflicts
  const int t = threadIdx.x;
  const int b = blockIdx.z & 15;
  const int which = blockIdx.z >> 4;
  const float* src = which ? k : q;
  u16* dst = which ? keffT : qT;
  const size_t inb = (size_t)b * H_ * N_;
  const size_t outb = (size_t)b * N_ * H_;
  const int n0 = blockIdx.x * 64;
  const int h0 = blockIdx.y * 64;
  const int col = t & 63;  // n offset, coalesced reads
  const int r0 = t >> 6;
#pragma unroll
  for (int i = 0; i < 16; ++i) {
    const int row = r0 + i * 4;  // h offset
    const size_t idx = inb + (size_t)(h0 + row) * N_ + (n0 + col);
    float v = src[idx];
    if (which) v += pe[idx];
    tile[row][col] = v;
  }
  __syncthreads();
  const int w = t & 31;   // h pair
  const int r1 = t >> 5;  // n sub-row
#pragma unroll
  for (int i = 0; i < 8; ++i) {
    const int row = r1 + i * 8;  // n offset
    const u32 u = pk2(tile[2 * w][row], tile[2 * w + 1][row]);
    *(u32*)(dst + outb + (size_t)(n0 + row) * H_ + (h0 + 2 * w)) = u;
  }
}

// ---------------------------------------------------------------------------
// K1: S[n][m] = qT[n][:] . keffT[m][:]   (K = 768), raw bf16 scores out.
// m97-style: 128x128 tile, 4 waves each 64x64, BK=32, 16B DMA staging.
__global__ __launch_bounds__(256) void k1_qk_gemm(
    const u16* __restrict__ qT, const u16* __restrict__ keffT, u16* __restrict__ S) {
  __shared__ __align__(16) u16 ldsA[128 * 32];
  __shared__ __align__(16) u16 ldsB[128 * 32];
  __shared__ __align__(16) float ldsC[32 * 132];  // chunked epilogue, padded
  const int t = threadIdx.x;
  const int lane = t & 63;
  const int wv = t >> 6;
  const int wr = wv >> 1, wc = wv & 1;
  const int b = blockIdx.z;
  const int m0 = blockIdx.x * 128;
  const int n0 = blockIdx.y * 128;
  const u16* Ab = qT + (size_t)b * N_ * H_ + (size_t)n0 * H_;    // rows n, stride H
  const u16* Bb = keffT + (size_t)b * N_ * H_ + (size_t)m0 * H_; // rows m, stride H
  float4v acc[4][4] = {};
  const int fr = lane & 15;
  const int fk = (lane >> 4) * 8;
  for (int k0 = 0; k0 < H_; k0 += 32) {
    __syncthreads();
#pragma unroll
    for (int r = 0; r < 2; ++r) {
      const int c = r * 256 + t;
      const int row = c >> 2;
      const int co = (c & 3) * 8;
      dma16(Ab + (size_t)row * H_ + (k0 + co), &ldsA[c * 8]);
      dma16(Bb + (size_t)row * H_ + (k0 + co), &ldsB[c * 8]);
    }
    __syncthreads();
    short8 af[4], bfv[4];
#pragma unroll
    for (int i = 0; i < 4; ++i)
      af[i] = *(const short8*)&ldsA[(wr * 64 + i * 16 + fr) * 32 + fk];
#pragma unroll
    for (int j = 0; j < 4; ++j)
      bfv[j] = *(const short8*)&ldsB[(wc * 64 + j * 16 + fr) * 32 + fk];
#pragma unroll
    for (int i = 0; i < 4; ++i)
#pragma unroll
      for (int j = 0; j < 4; ++j)
        acc[i][j] = __builtin_amdgcn_mfma_f32_16x16x32_bf16(af[i], bfv[j], acc[i][j], 0, 0, 0);
  }
  // epilogue: acc -> ldsC (32-row chunks) -> coalesced bf16 stores
  const int cr = lane >> 4;
  const int cc = lane & 15;
  const size_t Sb = (size_t)b * N_ * N_;
  const int orow = t >> 3;
  const int ocol = (t & 7) * 16;
  for (int chunk = 0; chunk < 4; ++chunk) {
    __syncthreads();
    if (wr == (chunk >> 1)) {
#pragma unroll
      for (int ii = 0; ii < 2; ++ii) {
        const int i = (chunk & 1) * 2 + ii;
#pragma unroll
        for (int j = 0; j < 4; ++j)
#pragma unroll
          for (int r = 0; r < 4; ++r)
            ldsC[(ii * 16 + cr * 4 + r) * 132 + (wc * 64 + j * 16 + cc)] = acc[i][j][r];
      }
    }
    __syncthreads();
    const float* srcp = &ldsC[orow * 132 + ocol];
    float4 fA = *(const float4*)&srcp[0];
    float4 fB = *(const float4*)&srcp[4];
    float4 fC = *(const float4*)&srcp[8];
    float4 fD = *(const float4*)&srcp[12];
    uint4 o0, o1;
    o0.x = pk2(fA.x, fA.y); o0.y = pk2(fA.z, fA.w);
    o0.z = pk2(fB.x, fB.y); o0.w = pk2(fB.z, fB.w);
    o1.x = pk2(fC.x, fC.y); o1.y = pk2(fC.z, fC.w);
    o1.z = pk2(fD.x, fD.y); o1.w = pk2(fD.z, fD.w);
    u16* dst = S + Sb + (size_t)(n0 + chunk * 32 + orow) * N_ + (m0 + ocol);
    *(uint4*)dst = o0;
    *(uint4*)(dst + 8) = o1;
  }
}

// ---------------------------------------------------------------------------
// K1b: row-wise softmax over m, in place.  One wave per row, 32 elems/lane.
__global__ __launch_bounds__(256) void k1b_softmax(u16* __restrict__ S) {
  const int t = threadIdx.x;
  const int lane = t & 63;
  const int wv = t >> 6;
  const size_t row = (size_t)blockIdx.x * 4 + wv;  // b*N + n
  u16* base = S + row * N_;
  float x[32];
#pragma unroll
  for (int c = 0; c < 4; ++c) {
    uint4 u = *(const uint4*)&base[c * 512 + lane * 8];
    const u32 uu[4] = {u.x, u.y, u.z, u.w};
#pragma unroll
    for (int e = 0; e < 4; ++e) {
      x[c * 8 + e * 2] = bf2f((u16)(uu[e] & 0xFFFFu));
      x[c * 8 + e * 2 + 1] = bf2f((u16)(uu[e] >> 16));
    }
  }
  float mx = -1e30f;
#pragma unroll
  for (int e = 0; e < 32; ++e) mx = fmaxf(mx, x[e]);
#pragma unroll
  for (int off = 32; off > 0; off >>= 1) mx = fmaxf(mx, __shfl_xor(mx, off));
  float sum = 0.f;
#pragma unroll
  for (int e = 0; e < 32; ++e) {
    x[e] = __expf((x[e] - mx) * SCALE);
    sum += x[e];
  }
#pragma unroll
  for (int off = 32; off > 0; off >>= 1) sum += __shfl_xor(sum, off);
  const float rinv = 1.0f / sum;
#pragma unroll
  for (int c = 0; c < 4; ++c) {
    uint4 o;
    o.x = pk2(x[c * 8 + 0] * rinv, x[c * 8 + 1] * rinv);
    o.y = pk2(x[c * 8 + 2] * rinv, x[c * 8 + 3] * rinv);
    o.z = pk2(x[c * 8 + 4] * rinv, x[c * 8 + 5] * rinv);
    o.w = pk2(x[c * 8 + 6] * rinv, x[c * 8 + 7] * rinv);
    *(uint4*)&base[c * 512 + lane * 8] = o;
  }
}

// ---------------------------------------------------------------------------
// K2: out[h][n] = sum_m v[h][m] * P[n][m]   (K = 2048).
// A (v, fp32) VALU-staged with cvt->bf16; B (P, bf16) DMA-staged.
__global__ __launch_bounds__(256) void k2_pv_gemm(
    const float* __restrict__ v, const u16* __restrict__ P, float* __restrict__ out) {
  __shared__ __align__(16) u16 ldsA[128 * 32];
  __shared__ __align__(16) u16 ldsB[128 * 32];
  const int t = threadIdx.x;
  const int lane = t & 63;
  const int wv = t >> 6;
  const int wr = wv >> 1, wc = wv & 1;
  const int b = blockIdx.z;
  const int n0 = blockIdx.x * 128;
  const int h0 = blockIdx.y * 128;
  const float* Ab = v + (size_t)b * H_ * N_ + (size_t)h0 * N_;  // rows h, stride N
  const u16* Bb = P + (size_t)b * N_ * N_ + (size_t)n0 * N_;    // rows n, stride N
  float4v acc[4][4] = {};
  const int fr = lane & 15;
  const int fk = (lane >> 4) * 8;
  for (int k0 = 0; k0 < N_; k0 += 32) {
    __syncthreads();
#pragma unroll
    for (int r = 0; r < 2; ++r) {
      const int c = r * 256 + t;
      dma16(Bb + (size_t)(c >> 2) * N_ + (k0 + (c & 3) * 8), &ldsB[c * 8]);
    }
#pragma unroll
    for (int it = 0; it < 4; ++it) {
      const int idx = (it * 256 + t) * 4;
      const int row = idx >> 5, col = idx & 31;
      float4 f = *(const float4*)&Ab[(size_t)row * N_ + (k0 + col)];
      uint2 u;
      u.x = pk2(f.x, f.y);
      u.y = pk2(f.z, f.w);
      *(uint2*)&ldsA[idx] = u;
    }
    __syncthreads();
    short8 af[4], bfv[4];
#pragma unroll
    for (int i = 0; i < 4; ++i)
      af[i] = *(const short8*)&ldsA[(wr * 64 + i * 16 + fr) * 32 + fk];
#pragma unroll
    for (int j = 0; j < 4; ++j)
      bfv[j] = *(const short8*)&ldsB[(wc * 64 + j * 16 + fr) * 32 + fk];
#pragma unroll
    for (int i = 0; i < 4; ++i)
#pragma unroll
      for (int j = 0; j < 4; ++j)
        acc[i][j] = __builtin_amdgcn_mfma_f32_16x16x32_bf16(af[i], bfv[j], acc[i][j], 0, 0, 0);
  }
  const int cr = lane >> 4, cc = lane & 15;
  const size_t ob = (size_t)b * H_ * N_;
#pragma unroll
  for (int i = 0; i < 4; ++i) {
    const int hh = h0 + wr * 64 + i * 16 + cr * 4;
#pragma unroll
    for (int j = 0; j < 4; ++j) {
      const int nn = n0 + wc * 64 + j * 16 + cc;
#pragma unroll
      for (int r = 0; r < 4; ++r)
        out[ob + (size_t)(hh + r) * N_ + nn] = acc[i][j][r];
    }
  }
}

// ---------------------------------------------------------------------------
extern "C" void kernel_launch(void* const* d_in, const int* in_sizes, int n_in,
                              void* d_out, int out_size, void* d_ws, size_t ws_size,
                              hipStream_t stream) {
  const float* q = (const float*)d_in[0];
  const float* k = (const float*)d_in[1];
  const float* v = (const float*)d_in[2];
  const float* pe = (const float*)d_in[3];
  float* out = (float*)d_out;
  char* ws = (char*)d_ws;
  // ws layout: qT (48 MiB) | keffT (48 MiB) | S/P (128 MiB)  => 224 MiB total
  u16* qT = (u16*)ws;
  u16* keffT = (u16*)(ws + 50331648);
  u16* S = (u16*)(ws + 100663296);

  hipLaunchKernelGGL(kt_transpose, dim3(32, 12, 32), dim3(256), 0, stream, q, k, pe, qT, keffT);
  hipLaunchKernelGGL(k1_qk_gemm, dim3(16, 16, 16), dim3(256), 0, stream, qT, keffT, S);
  hipLaunchKernelGGL(k1b_softmax, dim3(8192), dim3(256), 0, stream, S);
  hipLaunchKernelGGL(k2_pv_gemm, dim3(16, 6, 16), dim3(256), 0, stream, v, S, out);
}